// Round 2
// baseline (464.916 us; speedup 1.0000x reference)
//
#include <hip/hip_runtime.h>
#include <hip/hip_cooperative_groups.h>

namespace cg = cooperative_groups;

// Problem constants
#define DIMC 192
#define HID  48          // DIM / RED
#define HW   65536       // 256*256
#define NPLANE 768       // B * DIM
#define NBLK 256         // one block per CU, guaranteed co-resident
#define PPB 3            // planes per block (768 / 256)

// ---------------------------------------------------------------------------
// Fused cooperative kernel: pool -> (grid sync) -> dynamic weights ->
// (grid sync) -> 4-tap masked depthwise conv.
//
// 256 blocks x 1024 threads = 16 waves/block = 1 block/CU (VGPR budget 128,
// enforced by the 1024-thread launch bound). Block i owns planes [3i, 3i+3)
// for both pooling and conv, so phase-3 reads hit L2/L3 lines phase 1 pulled.
//
// Mask 'A' on a 3x3 leaves taps (0,0),(0,1),(0,2),(1,0):
//   out[y][x] = w00*X[y-1][x-1] + w01*X[y-1][x] + w02*X[y-1][x+1]
//             + w10*X[y][x-1] + bias[c]
// ---------------------------------------------------------------------------
__global__ __launch_bounds__(1024) void fused_kernel(
    const float* __restrict__ x,      // [4,192,256,256]
    const float* __restrict__ w1,     // [48,192]
    const float* __restrict__ gamma,
    const float* __restrict__ beta,
    const float* __restrict__ rmean,
    const float* __restrict__ rvar,
    const float* __restrict__ w2,     // [1728,48]
    const float* __restrict__ b2,     // [1728]
    const float* __restrict__ bias,   // [192]
    float* __restrict__ out,          // [4,192,256,256]
    float* __restrict__ pooled,       // ws: [768]
    float* __restrict__ w4v)          // ws: [768*4] (float4 per plane)
{
    cg::grid_group grid = cg::this_grid();
    const int blk  = blockIdx.x;
    const int t    = threadIdx.x;
    const int wave = t >> 6;
    const int lane = t & 63;

    __shared__ float wsum[16];
    __shared__ float T[HID];

    // ---- Phase 1: mean-pool planes 3b..3b+2 (each 256 KB, streaming read) ----
    for (int pi = 0; pi < PPB; ++pi) {
        const int plane = blk * PPB + pi;
        const float4* p = (const float4*)(x + (size_t)plane * HW);
        float s = 0.f;
#pragma unroll
        for (int k = 0; k < 16; ++k) {
            float4 v = p[k * 1024 + t];
            s += (v.x + v.y) + (v.z + v.w);
        }
#pragma unroll
        for (int off = 32; off > 0; off >>= 1) s += __shfl_down(s, off, 64);
        if (lane == 0) wsum[wave] = s;
        __syncthreads();
        if (t == 0) {
            float tot = 0.f;
#pragma unroll
            for (int i = 0; i < 16; ++i) tot += wsum[i];
            pooled[plane] = tot * (1.0f / 65536.0f);
        }
        __syncthreads();
    }
    grid.sync();

    // ---- Phase 2: dynamic weights, blocks 0..3 (one per sample) ----
    if (blk < 4) {
        if (t < HID) {
            const float* wr = w1 + t * DIMC;
            const float* P  = pooled + blk * DIMC;
            float acc = 0.f;
            for (int d = 0; d < DIMC; ++d) acc += P[d] * wr[d];
            const float inv = 1.0f / sqrtf(rvar[t] + 1e-5f);
            float v = gamma[t] * (acc - rmean[t]) * inv + beta[t];
            T[t] = v > 0.f ? v : 0.f;
        }
        __syncthreads();
        if (t < DIMC * 4) {                       // 768 outputs, threads 0..767
            const int c = t >> 2, tap = t & 3;
            const int o = c * 9 + tap;            // taps 0..3 of the 3x3 kernel
            const float* wr = w2 + o * HID;
            float acc = b2[o];
            for (int j = 0; j < HID; ++j) acc += T[j] * wr[j];
            w4v[blk * DIMC * 4 + t] = acc;
        }
    }
    grid.sync();

    // ---- Phase 3: 4-tap conv on the same 3 planes (reads hot from L2/L3) ----
    const float4* w4p = (const float4*)w4v;
    for (int pi = 0; pi < PPB; ++pi) {
        const int plane = blk * PPB + pi;
        const int c = plane % DIMC;
        const float4 wt = w4p[plane];             // {w00, w01, w02, w10}
        const float bs = bias[c];
        const float4* xp = (const float4*)(x + (size_t)plane * HW);
        float4* op = (float4*)(out + (size_t)plane * HW);

        const int y0 = wave << 4;                 // 16 rows per wave, 16 waves
        float4 a;                                 // rolling row y-1
        if (y0 == 0) a = make_float4(0.f, 0.f, 0.f, 0.f);
        else         a = xp[(y0 - 1) * 64 + lane];

#pragma unroll
        for (int r = 0; r < 16; ++r) {
            const int y = y0 + r;
            float4 bb = xp[y * 64 + lane];        // row y
            float leftA  = __shfl_up(a.w, 1, 64);   if (lane == 0)  leftA  = 0.f;
            float rightA = __shfl_down(a.x, 1, 64); if (lane == 63) rightA = 0.f;
            float leftB  = __shfl_up(bb.w, 1, 64);  if (lane == 0)  leftB  = 0.f;
            float4 o;
            o.x = wt.x * leftA + wt.y * a.x + wt.z * a.y    + wt.w * leftB + bs;
            o.y = wt.x * a.x   + wt.y * a.y + wt.z * a.z    + wt.w * bb.x  + bs;
            o.z = wt.x * a.y   + wt.y * a.z + wt.z * a.w    + wt.w * bb.y  + bs;
            o.w = wt.x * a.z   + wt.y * a.w + wt.z * rightA + wt.w * bb.z  + bs;
            op[y * 64 + lane] = o;
            a = bb;                               // roll: row y becomes row y-1
        }
    }
}

// ---------------------------------------------------------------------------
extern "C" void kernel_launch(void* const* d_in, const int* in_sizes, int n_in,
                              void* d_out, int out_size, void* d_ws, size_t ws_size,
                              hipStream_t stream) {
    const float* x     = (const float*)d_in[0];
    const float* w1    = (const float*)d_in[1];
    const float* gamma = (const float*)d_in[2];
    const float* beta  = (const float*)d_in[3];
    const float* rmean = (const float*)d_in[4];
    const float* rvar  = (const float*)d_in[5];
    const float* w2    = (const float*)d_in[6];
    const float* b2    = (const float*)d_in[7];
    const float* bias  = (const float*)d_in[8];
    float* out = (float*)d_out;

    float* pooled = (float*)d_ws;        // 768 floats
    float* w4     = pooled + NPLANE;     // 768 float4 = 3072 floats (16B aligned)

    void* args[] = {
        (void*)&x, (void*)&w1, (void*)&gamma, (void*)&beta, (void*)&rmean,
        (void*)&rvar, (void*)&w2, (void*)&b2, (void*)&bias, (void*)&out,
        (void*)&pooled, (void*)&w4,
    };
    hipLaunchCooperativeKernel((void*)fused_kernel, dim3(NBLK), dim3(1024),
                               args, 0, stream);
}